// Round 8
// baseline (24.456 us; speedup 1.0000x reference)
//
#include <hip/hip_runtime.h>

// SimpleRPMGLoss: out = mean(smooth_l1(pred[:,:3], tgt[:,:3]))
//               + 100 * mean(acos(clip((sum(R(pred_e)*R(tgt_e)) - 1)/2)))
// B = 2,097,152 rows x 6 f32 each input (~100 MB read). Memory-bound streaming
// reduction; k1 pinned at ~19.7us (5.1 TB/s) across all scheduling variants.
//
// This round: fix per-instruction coalescing. Direct per-thread row ownership
// makes every wave dwordx4 load stride 48 B -> touches 48 cache lines per 16
// lines of data (3x line-request/MSHR pressure). Stage each block's tile into
// LDS with UNIT-STRIDE global loads (wave-load = contiguous 1 KB = 16 lines),
// then read per-thread 48 B slices from LDS (ds_read_b128 x3, conflict-free:
// 8 lanes x 12-bank stride cover all 32 banks exactly once).
//
// Two-kernel structure retained (fused last-block-done REGRESSED: 2048
// same-line agent RMWs drain ~8-9 ns each serially => ~17us tail; ACQ_REL RMW
// adds per-block L2 wb/inv => 114us; counter mod-tricks race the finisher).

constexpr int   B_ROWS  = 2097152;
constexpr int   TPB     = 256;
constexpr int   NBLK    = 4096;             // 1 row-pair per thread, exact cover
constexpr int   PAIRS_PER_BLK = TPB;        // 256 pairs = 512 rows per block
constexpr float ANGLE_WEIGHT = 100.0f;
constexpr float EPS_F        = 1e-7f;

typedef float f32x4 __attribute__((ext_vector_type(4)));

__device__ inline float smooth_l1_term(float d) {
    float ad = fabsf(d);
    return ad < 1.0f ? 0.5f * d * d : ad - 0.5f;
}

__device__ inline void euler_xyz_mat(float a, float b, float c, float r[9]) {
    float sa, ca, sb, cb, sc, cc;
    __sincosf(a, &sa, &ca);
    __sincosf(b, &sb, &cb);
    __sincosf(c, &sc, &cc);
    r[0] = cb * cc;
    r[1] = cc * sa * sb - ca * sc;
    r[2] = sc * sa + ca * cc * sb;
    r[3] = cb * sc;
    r[4] = ca * cc + sa * sb * sc;
    r[5] = ca * sb * sc - cc * sa;
    r[6] = -sb;
    r[7] = cb * sa;
    r[8] = ca * cb;
}

__device__ inline void accum_row(float px, float py, float pz,
                                 float pa, float pb, float pc,
                                 float tx, float ty, float tz,
                                 float ta, float tb, float tc,
                                 float& trans_acc, float& rot_acc) {
    trans_acc += smooth_l1_term(px - tx) + smooth_l1_term(py - ty) + smooth_l1_term(pz - tz);
    float rp[9], rt[9];
    euler_xyz_mat(pa, pb, pc, rp);
    euler_xyz_mat(ta, tb, tc, rt);
    float tr = 0.0f;
#pragma unroll
    for (int i = 0; i < 9; ++i) tr = fmaf(rp[i], rt[i], tr);
    float cosang = fminf(fmaxf((tr - 1.0f) * 0.5f, -1.0f + EPS_F), 1.0f - EPS_F);
    rot_acc += acosf(cosang);
}

__global__ __launch_bounds__(TPB) void rpmg_partial_kernel(const float* __restrict__ pred,
                                                           const float* __restrict__ tgt,
                                                           float2* __restrict__ partial) {
    // Per-block tile: 256 pairs * 48 B = 12 KB per input, 24 KB LDS total
    // -> 6 blocks/CU co-resident (24 waves/CU).
    __shared__ f32x4 ldsA[3 * TPB];
    __shared__ f32x4 ldsB[3 * TPB];

    const int t = threadIdx.x;
    const size_t tile_x4 = (size_t)blockIdx.x * (3 * TPB);   // tile base in f32x4 units
    const f32x4* pbase = reinterpret_cast<const f32x4*>(pred) + tile_x4;
    const f32x4* tbase = reinterpret_cast<const f32x4*>(tgt)  + tile_x4;

    // Unit-stride staging: each wave-load is a contiguous 1 KB (16 lines).
#pragma unroll
    for (int k = 0; k < 3; ++k) ldsA[k * TPB + t] = pbase[k * TPB + t];
#pragma unroll
    for (int k = 0; k < 3; ++k) ldsB[k * TPB + t] = tbase[k * TPB + t];
    __syncthreads();

    // Each thread consumes its own pair (48 B) from LDS.
    f32x4 a0 = ldsA[t * 3 + 0], a1 = ldsA[t * 3 + 1], a2 = ldsA[t * 3 + 2];
    f32x4 b0 = ldsB[t * 3 + 0], b1 = ldsB[t * 3 + 1], b2 = ldsB[t * 3 + 2];

    float trans_acc = 0.0f, rot_acc = 0.0f;
    accum_row(a0[0], a0[1], a0[2], a0[3], a1[0], a1[1],
              b0[0], b0[1], b0[2], b0[3], b1[0], b1[1], trans_acc, rot_acc);
    accum_row(a1[2], a1[3], a2[0], a2[1], a2[2], a2[3],
              b1[2], b1[3], b2[0], b2[1], b2[2], b2[3], trans_acc, rot_acc);

    // Block reduction -> one float2 per block (plain store; dispatch-boundary
    // release/acquire makes it visible to kernel 2).
#pragma unroll
    for (int off = 32; off > 0; off >>= 1) {
        trans_acc += __shfl_down(trans_acc, off, 64);
        rot_acc   += __shfl_down(rot_acc,   off, 64);
    }
    __shared__ float sa[TPB / 64], sb[TPB / 64];
    const int wid  = threadIdx.x >> 6;
    const int lane = threadIdx.x & 63;
    if (lane == 0) { sa[wid] = trans_acc; sb[wid] = rot_acc; }
    __syncthreads();
    if (threadIdx.x == 0) {
        float ta = 0.0f, tb = 0.0f;
#pragma unroll
        for (int w = 0; w < TPB / 64; ++w) { ta += sa[w]; tb += sb[w]; }
        partial[blockIdx.x] = make_float2(ta, tb);
    }
}

__global__ __launch_bounds__(TPB) void rpmg_final_kernel(const float2* __restrict__ partial,
                                                         float* __restrict__ out) {
    // 4096 float2 partials read as 2048 float4 (fixed order -> deterministic).
    const float4* p4 = reinterpret_cast<const float4*>(partial);
    float ta = 0.0f, tb = 0.0f;
    for (int i = threadIdx.x; i < NBLK / 2; i += TPB) {
        float4 v = p4[i];
        ta += v.x + v.z;
        tb += v.y + v.w;
    }
#pragma unroll
    for (int off = 32; off > 0; off >>= 1) {
        ta += __shfl_down(ta, off, 64);
        tb += __shfl_down(tb, off, 64);
    }
    __shared__ float sa[TPB / 64], sb[TPB / 64];
    const int wid  = threadIdx.x >> 6;
    const int lane = threadIdx.x & 63;
    if (lane == 0) { sa[wid] = ta; sb[wid] = tb; }
    __syncthreads();
    if (threadIdx.x == 0) {
        float st = 0.0f, sr = 0.0f;
#pragma unroll
        for (int w = 0; w < TPB / 64; ++w) { st += sa[w]; sr += sb[w]; }
        out[0] = st / (3.0f * (float)B_ROWS) + ANGLE_WEIGHT * (sr / (float)B_ROWS);
    }
}

extern "C" void kernel_launch(void* const* d_in, const int* in_sizes, int n_in,
                              void* d_out, int out_size, void* d_ws, size_t ws_size,
                              hipStream_t stream) {
    const float* pred = (const float*)d_in[0];
    const float* tgt  = (const float*)d_in[1];
    float* out        = (float*)d_out;
    float2* partial   = (float2*)d_ws;      // 32 KB scratch

    rpmg_partial_kernel<<<NBLK, TPB, 0, stream>>>(pred, tgt, partial);
    rpmg_final_kernel<<<1, TPB, 0, stream>>>(partial, out);
}